// Round 4
// baseline (1619.816 us; speedup 1.0000x reference)
//
#include <hip/hip_runtime.h>
#include <math.h>

#define N_NODES 100000
#define N_EDGES 6400000
#define F_IN 36
#define HID 8
#define NCLS 2
#define NEG_SLOPE 0.2f

#define NPB 64                      // nodes per fine bucket
#define NB  1563                    // ceil(N_NODES/64) fine buckets
#define NBC 98                      // ceil(N_NODES/1024) coarse buckets
#define SCAP 128                    // staging capacity per coarse bucket
#define CAP 6144                    // max edges per fine bucket (mean 4096 + 32 sigma)
#define SHIFT1 8.0f                 // softmax shift (softmax is shift-invariant)
#define SHIFT2 16.0f
#define CPX 196                     // ceil(NB/8) fine buckets per XCD for swizzle

// ---------------- K0: per-node h1 = x@W1, s1s = h1.a_src, s1d = h1.a_dst ----
__global__ __launch_bounds__(256) void k0_node(
    const float* __restrict__ x, const float* __restrict__ W1,
    const float* __restrict__ a1s_g, const float* __restrict__ a1d_g,
    float* __restrict__ h1, float* __restrict__ s1s, float* __restrict__ s1d)
{
    __shared__ float sW[F_IN * HID];
    __shared__ float sas[HID], sad[HID];
    int tid = threadIdx.x;
    for (int i = tid; i < F_IN * HID; i += 256) sW[i] = W1[i];
    if (tid < HID) { sas[tid] = a1s_g[tid]; sad[tid] = a1d_g[tid]; }
    __syncthreads();

    int n = blockIdx.x * 256 + tid;
    if (n >= N_NODES) return;

    const float4* xp = (const float4*)(x + (size_t)n * F_IN);
    float h[HID];
#pragma unroll
    for (int f = 0; f < HID; ++f) h[f] = 0.f;
#pragma unroll
    for (int q = 0; q < F_IN / 4; ++q) {
        float4 v = xp[q];
        float vs[4] = {v.x, v.y, v.z, v.w};
#pragma unroll
        for (int j = 0; j < 4; ++j) {
            int k = q * 4 + j;
#pragma unroll
            for (int f = 0; f < HID; ++f) h[f] = fmaf(vs[j], sW[k * HID + f], h[f]);
        }
    }
    float ss = 0.f, sd = 0.f;
#pragma unroll
    for (int f = 0; f < HID; ++f) { ss = fmaf(h[f], sas[f], ss); sd = fmaf(h[f], sad[f], sd); }

    float4* hp = (float4*)(h1 + (size_t)n * HID);
    hp[0] = make_float4(h[0], h[1], h[2], h[3]);
    hp[1] = make_float4(h[4], h[5], h[6], h[7]);
    s1s[n] = ss;
    s1d[n] = sd;
}

// ---------------- KB1: fine-bucket histogram over dst ----------------------
__global__ __launch_bounds__(256) void kb_hist(const int* __restrict__ dst, int* __restrict__ hist)
{
    __shared__ int lh[NB];
    int tid = threadIdx.x;
    for (int i = tid; i < NB; i += 256) lh[i] = 0;
    __syncthreads();
    const int4* dv = (const int4*)dst;
    int total4 = N_EDGES / 4;
    for (int i = blockIdx.x * 256 + tid; i < total4; i += gridDim.x * 256) {
        int4 d = dv[i];
        atomicAdd(&lh[d.x >> 6], 1);
        atomicAdd(&lh[d.y >> 6], 1);
        atomicAdd(&lh[d.z >> 6], 1);
        atomicAdd(&lh[d.w >> 6], 1);
    }
    __syncthreads();
    for (int i = tid; i < NB; i += 256) if (lh[i]) atomicAdd(&hist[i], lh[i]);
}

// ---------------- KB2: scan NB fine counts; init coarse cursors ------------
__global__ __launch_bounds__(1024) void kb_scan(const int* __restrict__ hist,
                                                int* __restrict__ bptr, int* __restrict__ gcur)
{
    __shared__ int s[1024];
    int tid = threadIdx.x;
    int i0 = 2 * tid, i1 = 2 * tid + 1;
    int v0 = (i0 < NB) ? hist[i0] : 0;
    int v1 = (i1 < NB) ? hist[i1] : 0;
    s[tid] = v0 + v1;
    __syncthreads();
    for (int off = 1; off < 1024; off <<= 1) {
        int t = (tid >= off) ? s[tid - off] : 0;
        __syncthreads();
        s[tid] += t;
        __syncthreads();
    }
    int ex = s[tid] - (v0 + v1);
    if (i0 < NB) bptr[i0] = ex;
    if (i1 < NB) bptr[i1] = ex + v0;
    if (tid == 0) bptr[NB] = N_EDGES;
    // coarse bucket c starts at fine bucket 16c: exclusive prefix = s[8c-1]
    if (tid < NBC) gcur[tid] = (tid == 0) ? 0 : s[8 * tid - 1];
}

// ---------------- KB3: coarse scatter with LDS staging (coalesced flush) ---
__global__ __launch_bounds__(256) void kb_scatter2(
    const int* __restrict__ src, const int* __restrict__ dst,
    int* __restrict__ gcur, unsigned int* __restrict__ bdata)
{
    __shared__ int lcnt[NBC];
    __shared__ unsigned int stg[NBC * SCAP];   // ~50 KB
    int tid = threadIdx.x;
    for (int i = tid; i < NBC; i += 256) lcnt[i] = 0;
    __syncthreads();

    int e0 = blockIdx.x * 4096;
    int n4 = (N_EDGES - e0) >> 2; if (n4 > 1024) n4 = 1024;
    const int4* sv = (const int4*)(src + e0);
    const int4* dv = (const int4*)(dst + e0);

    for (int i = tid; i < n4; i += 256) {
        int4 s = sv[i], d = dv[i];
        int b, p;
        b = d.x >> 10; p = atomicAdd(&lcnt[b], 1); stg[b * SCAP + p] = (unsigned)s.x | ((unsigned)(d.x & 1023) << 17);
        b = d.y >> 10; p = atomicAdd(&lcnt[b], 1); stg[b * SCAP + p] = (unsigned)s.y | ((unsigned)(d.y & 1023) << 17);
        b = d.z >> 10; p = atomicAdd(&lcnt[b], 1); stg[b * SCAP + p] = (unsigned)s.z | ((unsigned)(d.z & 1023) << 17);
        b = d.w >> 10; p = atomicAdd(&lcnt[b], 1); stg[b * SCAP + p] = (unsigned)s.w | ((unsigned)(d.w & 1023) << 17);
    }
    __syncthreads();

    int wid = tid >> 6, lane = tid & 63;
    for (int b = wid; b < NBC; b += 4) {
        int cnt = lcnt[b];
        int base = 0;
        if (lane == 0 && cnt) base = atomicAdd(&gcur[b], cnt);
        base = __shfl(base, 0);
        for (int i = lane; i < cnt; i += 64) bdata[base + i] = stg[b * SCAP + i];
    }
}

// ---------------- K4: layer-1 agg — filtered read + LDS sort + reg accum ---
__global__ __launch_bounds__(256) void k_agg1(
    const int* __restrict__ bptr, const unsigned int* __restrict__ bdata,
    const float* __restrict__ h1, const float* __restrict__ s1s, const float* __restrict__ s1d,
    const float* __restrict__ b1, const float* __restrict__ W2,
    const float* __restrict__ a2s, const float* __restrict__ a2d,
    float* __restrict__ h2, float* __restrict__ s2s, float* __restrict__ s2d)
{
    __shared__ unsigned int raw[CAP];
    __shared__ unsigned int eidx[CAP];
    __shared__ int lcnt[NPB];
    __shared__ int locc[NPB];
    __shared__ int sstart[NPB + 1];
    __shared__ float sdv[NPB];
    __shared__ int nraw;

    int tid = threadIdx.x;
    // XCD swizzle: sibling fine buckets of one coarse bucket -> same XCD L2
    int b = (blockIdx.x & 7) * CPX + (blockIdx.x >> 3);
    if (b >= NB) return;
    int c = b >> 4;
    unsigned w = (unsigned)(b & 15);
    int node0 = b * NPB;

    int cb0 = bptr[c << 4];
    int cfhi = (c + 1) << 4; if (cfhi > NB) cfhi = NB;
    int cb1 = bptr[cfhi];

    if (tid < NPB) {
        lcnt[tid] = 0;
        sdv[tid] = (node0 + tid < N_NODES) ? s1d[node0 + tid] : 0.f;
    }
    if (tid == 0) nraw = 0;
    __syncthreads();

    // phase A: filtered append (wave-aggregated) + per-node count
    int lane = tid & 63;
    int nIter = (cb1 - cb0 + 255) >> 8;
    for (int it = 0; it < nIter; ++it) {
        int i = cb0 + (it << 8) + tid;
        unsigned pk = 0;
        bool m = false;
        if (i < cb1) { pk = bdata[i]; m = ((pk >> 23) == w); }
        unsigned long long mask = __ballot(m);
        if (mask) {
            int leader = __ffsll((unsigned long long)mask) - 1;
            int base = 0;
            if (lane == leader) base = atomicAdd(&nraw, __popcll(mask));
            base = __shfl(base, leader);
            if (m) {
                int rank = __popcll(mask & ((1ull << lane) - 1));
                raw[base + rank] = pk;
                atomicAdd(&lcnt[(pk >> 17) & 63], 1);
            }
        }
    }
    __syncthreads();

    // phase B: exclusive scan of 64 counters (wave 0)
    if (tid < 64) {
        int cc = lcnt[tid];
        int inc = cc;
#pragma unroll
        for (int off = 1; off < 64; off <<= 1) {
            int t2 = __shfl_up(inc, off);
            if (tid >= off) inc += t2;
        }
        sstart[tid] = inc - cc;
        locc[tid]   = inc - cc;
        if (tid == 63) sstart[64] = inc;
    }
    __syncthreads();

    // phase C: LDS->LDS counting-sort scatter
    int ne = nraw;
    for (int j = tid; j < ne; j += 256) {
        unsigned pk = raw[j];
        int p = atomicAdd(&locc[(pk >> 17) & 63], 1);
        eidx[p] = pk;
    }
    __syncthreads();

    // phase D: 4 threads per node, register accumulate
    int n = tid >> 2, q = tid & 3;
    int s0 = sstart[n], s1e = sstart[n + 1];
    float sdvn = sdv[n];
    float z = 0.f;
    float acc[HID];
#pragma unroll
    for (int f = 0; f < HID; ++f) acc[f] = 0.f;

    for (int j = s0 + q; j < s1e; j += 4) {
        unsigned pk = eidx[j];
        int s = pk & 0x1FFFF;
        float e = s1s[s] + sdvn;
        e = (e > 0.f) ? e : NEG_SLOPE * e;
        float p = __expf(e - SHIFT1);
        const float4* hp = (const float4*)(h1 + (size_t)s * HID);
        float4 h0 = hp[0], h4 = hp[1];
        z += p;
        acc[0] += p * h0.x; acc[1] += p * h0.y; acc[2] += p * h0.z; acc[3] += p * h0.w;
        acc[4] += p * h4.x; acc[5] += p * h4.y; acc[6] += p * h4.z; acc[7] += p * h4.w;
    }

#pragma unroll
    for (int off = 1; off < 4; off <<= 1) {
        z += __shfl_xor(z, off);
#pragma unroll
        for (int f = 0; f < HID; ++f) acc[f] += __shfl_xor(acc[f], off);
    }

    if (q == 0 && node0 + n < N_NODES) {
        int nd = node0 + n;
        float inv = 1.f / (z + 1e-16f);
        float c0 = 0.f, c1 = 0.f;
#pragma unroll
        for (int f = 0; f < HID; ++f) {
            float hr = fmaxf(acc[f] * inv + b1[f], 0.f);
            c0 = fmaf(hr, W2[f * NCLS + 0], c0);
            c1 = fmaf(hr, W2[f * NCLS + 1], c1);
        }
        ((float2*)h2)[nd] = make_float2(c0, c1);
        s2s[nd] = c0 * a2s[0] + c1 * a2s[1];
        s2d[nd] = c0 * a2d[0] + c1 * a2d[1];
    }
}

// ---------------- K5: layer-2 agg — filtered read + privatized LDS accum ---
__global__ __launch_bounds__(256) void k_agg2(
    const int* __restrict__ bptr, const unsigned int* __restrict__ bdata,
    const float* __restrict__ h2, const float* __restrict__ s2s, const float* __restrict__ s2d,
    const float* __restrict__ b2, float* __restrict__ out)
{
    __shared__ unsigned int raw[CAP];
    __shared__ float acc[4][NPB][3];    // per-wave privatized [z, a0, a1]
    __shared__ float sdv[NPB];
    __shared__ int nraw;

    int tid = threadIdx.x;
    int b = (blockIdx.x & 7) * CPX + (blockIdx.x >> 3);
    if (b >= NB) return;
    int c = b >> 4;
    unsigned w = (unsigned)(b & 15);
    int node0 = b * NPB;

    int cb0 = bptr[c << 4];
    int cfhi = (c + 1) << 4; if (cfhi > NB) cfhi = NB;
    int cb1 = bptr[cfhi];

    if (tid < NPB) {
        sdv[tid] = (node0 + tid < N_NODES) ? s2d[node0 + tid] : 0.f;
#pragma unroll
        for (int qq = 0; qq < 4; ++qq) {
            acc[qq][tid][0] = 0.f; acc[qq][tid][1] = 0.f; acc[qq][tid][2] = 0.f;
        }
    }
    if (tid == 0) nraw = 0;
    __syncthreads();

    // phase A: filtered append
    int lane = tid & 63;
    int nIter = (cb1 - cb0 + 255) >> 8;
    for (int it = 0; it < nIter; ++it) {
        int i = cb0 + (it << 8) + tid;
        unsigned pk = 0;
        bool m = false;
        if (i < cb1) { pk = bdata[i]; m = ((pk >> 23) == w); }
        unsigned long long mask = __ballot(m);
        if (mask) {
            int leader = __ffsll((unsigned long long)mask) - 1;
            int base = 0;
            if (lane == leader) base = atomicAdd(&nraw, __popcll(mask));
            base = __shfl(base, leader);
            if (m) {
                int rank = __popcll(mask & ((1ull << lane) - 1));
                raw[base + rank] = pk;
            }
        }
    }
    __syncthreads();

    // phase B: accumulate with per-wave privatized LDS atomics (3 per edge)
    int ne = nraw;
    int wid = tid >> 6;
    for (int j = tid; j < ne; j += 256) {
        unsigned pk = raw[j];
        int s = pk & 0x1FFFF;
        int loc = (pk >> 17) & 63;
        float e = s2s[s] + sdv[loc];
        e = (e > 0.f) ? e : NEG_SLOPE * e;
        float p = __expf(e - SHIFT2);
        float2 hv = ((const float2*)h2)[s];
        atomicAdd(&acc[wid][loc][0], p);
        atomicAdd(&acc[wid][loc][1], p * hv.x);
        atomicAdd(&acc[wid][loc][2], p * hv.y);
    }
    __syncthreads();

    if (tid < NPB && node0 + tid < N_NODES) {
        float z  = acc[0][tid][0] + acc[1][tid][0] + acc[2][tid][0] + acc[3][tid][0];
        float a0 = acc[0][tid][1] + acc[1][tid][1] + acc[2][tid][1] + acc[3][tid][1];
        float a1 = acc[0][tid][2] + acc[1][tid][2] + acc[2][tid][2] + acc[3][tid][2];
        float inv = 1.f / (z + 1e-16f);
        float o0 = a0 * inv + b2[0];
        float o1 = a1 * inv + b2[1];
        float mx = fmaxf(o0, o1);
        float lse = mx + __logf(__expf(o0 - mx) + __expf(o1 - mx));
        ((float2*)out)[node0 + tid] = make_float2(o0 - lse, o1 - lse);
    }
}

// ---------------- host launch ----------------------------------------------
extern "C" void kernel_launch(void* const* d_in, const int* in_sizes, int n_in,
                              void* d_out, int out_size, void* d_ws, size_t ws_size,
                              hipStream_t stream) {
    const float* x   = (const float*)d_in[0];
    const float* W1  = (const float*)d_in[1];
    const float* a1s = (const float*)d_in[2];
    const float* a1d = (const float*)d_in[3];
    const float* b1  = (const float*)d_in[4];
    const float* W2  = (const float*)d_in[5];
    const float* a2s = (const float*)d_in[6];
    const float* a2d = (const float*)d_in[7];
    const float* b2  = (const float*)d_in[8];
    const int*   ei  = (const int*)d_in[9];
    const int* src = ei;
    const int* dst = ei + N_EDGES;

    char* ws = (char*)d_ws;
    float* h1    = (float*)(ws + 0);              // 3,200,000
    float* s1s   = (float*)(ws + 3200000);        //   400,000
    float* s1d   = (float*)(ws + 3600000);        //   400,000
    float* h2    = (float*)(ws + 4000000);        //   800,000
    float* s2s   = (float*)(ws + 4800000);        //   400,000
    float* s2d   = (float*)(ws + 5200000);        //   400,000
    int*   hist  = (int*)  (ws + 5600000);        //     6,252
    int*   bptr  = (int*)  (ws + 5606272);        //     6,256
    int*   gcur  = (int*)  (ws + 5612544);        //       392
    unsigned int* bdata = (unsigned int*)(ws + 5612944);  // 25,600,000

    float* out = (float*)d_out;

    hipMemsetAsync(hist, 0, NB * sizeof(int), stream);

    k0_node<<<(N_NODES + 255) / 256, 256, 0, stream>>>(x, W1, a1s, a1d, h1, s1s, s1d);
    kb_hist<<<512, 256, 0, stream>>>(dst, hist);
    kb_scan<<<1, 1024, 0, stream>>>(hist, bptr, gcur);
    kb_scatter2<<<(N_EDGES + 4095) / 4096, 256, 0, stream>>>(src, dst, gcur, bdata);
    k_agg1<<<8 * CPX, 256, 0, stream>>>(bptr, bdata, h1, s1s, s1d, b1, W2, a2s, a2d,
                                        h2, s2s, s2d);
    k_agg2<<<8 * CPX, 256, 0, stream>>>(bptr, bdata, h2, s2s, s2d, b2, out);
}

// Round 5
// 528.543 us; speedup vs baseline: 3.0647x; 3.0647x over previous
//
#include <hip/hip_runtime.h>
#include <math.h>

#define N_NODES 100000
#define N_EDGES 6400000
#define F_IN 36
#define HID 8
#define NCLS 2
#define NEG_SLOPE 0.2f

#define COARSE 256                        // nodes per coarse bucket (dst >> 8)
#define NBC 391                           // ceil(N_NODES/256)
#define CAPC 18432                        // max edges per coarse bucket (mean 16384, +16 sigma)
#define NA_BLOCKS 256                     // pass-A blocks
#define EPB (N_EDGES / NA_BLOCKS)         // 25000 edges per pass-A block
#define SHIFT1 8.0f                       // softmax shift (softmax is shift-invariant)
#define SHIFT2 16.0f

// ---------------- K0: per-node h1 = x@W1, s1s = h1.a_src, s1d = h1.a_dst ----
__global__ __launch_bounds__(256) void k0_node(
    const float* __restrict__ x, const float* __restrict__ W1,
    const float* __restrict__ a1s_g, const float* __restrict__ a1d_g,
    float* __restrict__ h1, float* __restrict__ s1s, float* __restrict__ s1d)
{
    __shared__ float sW[F_IN * HID];
    __shared__ float sas[HID], sad[HID];
    int tid = threadIdx.x;
    for (int i = tid; i < F_IN * HID; i += 256) sW[i] = W1[i];
    if (tid < HID) { sas[tid] = a1s_g[tid]; sad[tid] = a1d_g[tid]; }
    __syncthreads();

    int n = blockIdx.x * 256 + tid;
    if (n >= N_NODES) return;

    const float4* xp = (const float4*)(x + (size_t)n * F_IN);
    float h[HID];
#pragma unroll
    for (int f = 0; f < HID; ++f) h[f] = 0.f;
#pragma unroll
    for (int q = 0; q < F_IN / 4; ++q) {
        float4 v = xp[q];
        float vs[4] = {v.x, v.y, v.z, v.w};
#pragma unroll
        for (int j = 0; j < 4; ++j) {
            int k = q * 4 + j;
#pragma unroll
            for (int f = 0; f < HID; ++f) h[f] = fmaf(vs[j], sW[k * HID + f], h[f]);
        }
    }
    float ss = 0.f, sd = 0.f;
#pragma unroll
    for (int f = 0; f < HID; ++f) { ss = fmaf(h[f], sas[f], ss); sd = fmaf(h[f], sad[f], sd); }

    float4* hp = (float4*)(h1 + (size_t)n * HID);
    hp[0] = make_float4(h[0], h[1], h[2], h[3]);
    hp[1] = make_float4(h[4], h[5], h[6], h[7]);
    s1s[n] = ss;
    s1d[n] = sd;
}

// ---------------- K1: node-level degree histogram (independent atomics) ----
__global__ __launch_bounds__(256) void k_hist(const int* __restrict__ dst, int* __restrict__ deg)
{
    int i = blockIdx.x * 256 + threadIdx.x;          // exactly N_EDGES/4 threads
    const int4* dv = (const int4*)dst;
    int4 d = dv[i];
    atomicAdd(&deg[d.x], 1);
    atomicAdd(&deg[d.y], 1);
    atomicAdd(&deg[d.z], 1);
    atomicAdd(&deg[d.w], 1);
}

// ---------------- K2a: per-coarse-bucket edge counts -----------------------
__global__ __launch_bounds__(256) void k2a_csum(const int* __restrict__ deg, int* __restrict__ ccnt)
{
    __shared__ int s[256];
    int b = blockIdx.x, tid = threadIdx.x;
    int idx = b * COARSE + tid;
    s[tid] = (idx < N_NODES) ? deg[idx] : 0;
    __syncthreads();
    for (int off = 128; off > 0; off >>= 1) {
        if (tid < off) s[tid] += s[tid + off];
        __syncthreads();
    }
    if (tid == 0) ccnt[b] = s[0];
}

// ---------------- K2b: scan coarse counts; init padded cursors -------------
__global__ __launch_bounds__(512) void k2b_cscan(const int* __restrict__ ccnt,
                                                 int* __restrict__ cbase, int* __restrict__ cursC)
{
    __shared__ int s[512];
    int tid = threadIdx.x;
    int v = (tid < NBC) ? ccnt[tid] : 0;
    s[tid] = v;
    __syncthreads();
    for (int off = 1; off < 512; off <<= 1) {
        int t = (tid >= off) ? s[tid - off] : 0;
        __syncthreads();
        s[tid] += t;
        __syncthreads();
    }
    int ex = s[tid] - v;
    if (tid < NBC) { cbase[tid] = ex; cursC[tid * 16] = ex; }
    if (tid == NBC) cbase[NBC] = ex;   // == N_EDGES
}

// ---------------- K2c: node-level CSR pointers -----------------------------
__global__ __launch_bounds__(256) void k2c_nptr(const int* __restrict__ deg,
                                                const int* __restrict__ cbase, int* __restrict__ nptr)
{
    __shared__ int s[256];
    int b = blockIdx.x, tid = threadIdx.x;
    int idx = b * COARSE + tid;
    int v = (idx < N_NODES) ? deg[idx] : 0;
    s[tid] = v;
    __syncthreads();
    for (int off = 1; off < 256; off <<= 1) {
        int t = (tid >= off) ? s[tid - off] : 0;
        __syncthreads();
        s[tid] += t;
        __syncthreads();
    }
    int ex = s[tid] - v + cbase[b];
    if (idx <= N_NODES) nptr[idx] = ex;
}

// ---------------- KA: coarse scatter (391 buckets, padded cursors) ---------
__global__ __launch_bounds__(256) void kA_scatter(
    const int* __restrict__ src, const int* __restrict__ dst,
    int* __restrict__ cursC, unsigned int* __restrict__ bdata)
{
    __shared__ int lh[NBC];
    __shared__ int lc[NBC];
    int tid = threadIdx.x;
    for (int i = tid; i < NBC; i += 256) lh[i] = 0;
    __syncthreads();

    int e0 = blockIdx.x * EPB;
    const int4* sv = (const int4*)(src + e0);
    const int4* dv = (const int4*)(dst + e0);
    const int n4 = EPB / 4;                       // 6250

    for (int i = tid; i < n4; i += 256) {
        int4 d = dv[i];
        atomicAdd(&lh[d.x >> 8], 1);
        atomicAdd(&lh[d.y >> 8], 1);
        atomicAdd(&lh[d.z >> 8], 1);
        atomicAdd(&lh[d.w >> 8], 1);
    }
    __syncthreads();
    for (int b = tid; b < NBC; b += 256) {
        int c = lh[b];
        lc[b] = c ? atomicAdd(&cursC[b * 16], c) : 0;   // one line per cursor, independent
    }
    __syncthreads();
    for (int i = tid; i < n4; i += 256) {
        int4 d = dv[i];
        int4 s = sv[i];
        int b, p;
        b = d.x >> 8; p = atomicAdd(&lc[b], 1); bdata[p] = (unsigned)s.x | ((unsigned)(d.x & 255) << 17);
        b = d.y >> 8; p = atomicAdd(&lc[b], 1); bdata[p] = (unsigned)s.y | ((unsigned)(d.y & 255) << 17);
        b = d.z >> 8; p = atomicAdd(&lc[b], 1); bdata[p] = (unsigned)s.z | ((unsigned)(d.z & 255) << 17);
        b = d.w >> 8; p = atomicAdd(&lc[b], 1); bdata[p] = (unsigned)s.w | ((unsigned)(d.w & 255) << 17);
    }
}

// ---------------- KB: in-LDS node-granularity sort (in-place, per bucket) --
__global__ __launch_bounds__(256) void kB_sort(
    const int* __restrict__ cbase, unsigned int* __restrict__ bdata)
{
    __shared__ unsigned int raw[CAPC];    // 72 KB
    __shared__ int cnt[COARSE];
    __shared__ int cur[COARSE];
    int tid = threadIdx.x;
    int c = blockIdx.x;
    int cb0 = cbase[c], cb1 = cbase[c + 1];
    int ne = cb1 - cb0;

    cnt[tid] = 0;
    __syncthreads();

    for (int i = tid; i < ne; i += 256) {
        unsigned pk = bdata[cb0 + i];
        raw[i] = pk;
        atomicAdd(&cnt[pk >> 17], 1);     // no return needed -> independent
    }
    __syncthreads();

    int v = cnt[tid];
    for (int off = 1; off < 256; off <<= 1) {
        int t = (tid >= off) ? cnt[tid - off] : 0;
        __syncthreads();
        cnt[tid] += t;
        __syncthreads();
    }
    cur[tid] = cnt[tid] - v;              // exclusive within-bucket offset
    __syncthreads();

    for (int i = tid; i < ne; i += 256) {
        unsigned pk = raw[i];
        int loc = pk >> 17;
        int p = atomicAdd(&cur[loc], 1);
        bdata[cb0 + p] = pk & 0x1FFFF;    // node-sorted: store src only
    }
}

// ---------------- KAgg1: layer-1 CSR aggregation (4 threads/node) ----------
__global__ __launch_bounds__(256) void kAgg1(
    const int* __restrict__ nptr, const unsigned int* __restrict__ bdata,
    const float* __restrict__ h1, const float* __restrict__ s1s, const float* __restrict__ s1d,
    const float* __restrict__ b1, const float* __restrict__ W2,
    const float* __restrict__ a2s, const float* __restrict__ a2d,
    float* __restrict__ h2, float* __restrict__ s2s, float* __restrict__ s2d)
{
    int gi = blockIdx.x * 256 + threadIdx.x;
    int n = gi >> 2, q = gi & 3;
    if (n >= N_NODES) return;

    int e0 = nptr[n], e1 = nptr[n + 1];
    float sdvn = s1d[n];
    float z = 0.f;
    float acc[HID];
#pragma unroll
    for (int f = 0; f < HID; ++f) acc[f] = 0.f;

    for (int j = e0 + q; j < e1; j += 4) {
        int s = bdata[j];
        float e = s1s[s] + sdvn;
        e = (e > 0.f) ? e : NEG_SLOPE * e;
        float p = __expf(e - SHIFT1);
        const float4* hp = (const float4*)(h1 + (size_t)s * HID);
        float4 h0 = hp[0], h4 = hp[1];
        z += p;
        acc[0] += p * h0.x; acc[1] += p * h0.y; acc[2] += p * h0.z; acc[3] += p * h0.w;
        acc[4] += p * h4.x; acc[5] += p * h4.y; acc[6] += p * h4.z; acc[7] += p * h4.w;
    }

#pragma unroll
    for (int off = 1; off < 4; off <<= 1) {
        z += __shfl_xor(z, off);
#pragma unroll
        for (int f = 0; f < HID; ++f) acc[f] += __shfl_xor(acc[f], off);
    }

    if (q == 0) {
        float inv = 1.f / (z + 1e-16f);
        float c0 = 0.f, c1 = 0.f;
#pragma unroll
        for (int f = 0; f < HID; ++f) {
            float hr = fmaxf(acc[f] * inv + b1[f], 0.f);
            c0 = fmaf(hr, W2[f * NCLS + 0], c0);
            c1 = fmaf(hr, W2[f * NCLS + 1], c1);
        }
        ((float2*)h2)[n] = make_float2(c0, c1);
        s2s[n] = c0 * a2s[0] + c1 * a2s[1];
        s2d[n] = c0 * a2d[0] + c1 * a2d[1];
    }
}

// ---------------- KAgg2: layer-2 CSR aggregation + log_softmax -------------
__global__ __launch_bounds__(256) void kAgg2(
    const int* __restrict__ nptr, const unsigned int* __restrict__ bdata,
    const float* __restrict__ h2, const float* __restrict__ s2s, const float* __restrict__ s2d,
    const float* __restrict__ b2, float* __restrict__ out)
{
    int gi = blockIdx.x * 256 + threadIdx.x;
    int n = gi >> 2, q = gi & 3;
    if (n >= N_NODES) return;

    int e0 = nptr[n], e1 = nptr[n + 1];
    float sdvn = s2d[n];
    float z = 0.f, a0 = 0.f, a1 = 0.f;

    for (int j = e0 + q; j < e1; j += 4) {
        int s = bdata[j];
        float e = s2s[s] + sdvn;
        e = (e > 0.f) ? e : NEG_SLOPE * e;
        float p = __expf(e - SHIFT2);
        float2 hv = ((const float2*)h2)[s];
        z += p; a0 += p * hv.x; a1 += p * hv.y;
    }

#pragma unroll
    for (int off = 1; off < 4; off <<= 1) {
        z  += __shfl_xor(z, off);
        a0 += __shfl_xor(a0, off);
        a1 += __shfl_xor(a1, off);
    }

    if (q == 0) {
        float inv = 1.f / (z + 1e-16f);
        float o0 = a0 * inv + b2[0];
        float o1 = a1 * inv + b2[1];
        float mx = fmaxf(o0, o1);
        float lse = mx + __logf(__expf(o0 - mx) + __expf(o1 - mx));
        ((float2*)out)[n] = make_float2(o0 - lse, o1 - lse);
    }
}

// ---------------- host launch ----------------------------------------------
extern "C" void kernel_launch(void* const* d_in, const int* in_sizes, int n_in,
                              void* d_out, int out_size, void* d_ws, size_t ws_size,
                              hipStream_t stream) {
    const float* x   = (const float*)d_in[0];
    const float* W1  = (const float*)d_in[1];
    const float* a1s = (const float*)d_in[2];
    const float* a1d = (const float*)d_in[3];
    const float* b1  = (const float*)d_in[4];
    const float* W2  = (const float*)d_in[5];
    const float* a2s = (const float*)d_in[6];
    const float* a2d = (const float*)d_in[7];
    const float* b2  = (const float*)d_in[8];
    const int*   ei  = (const int*)d_in[9];
    const int* src = ei;
    const int* dst = ei + N_EDGES;

    char* ws = (char*)d_ws;
    float* h1    = (float*)(ws + 0);               // 3,200,000
    float* s1s   = (float*)(ws + 3200000);         //   400,000
    float* s1d   = (float*)(ws + 3600000);         //   400,000
    float* h2    = (float*)(ws + 4000000);         //   800,000
    float* s2s   = (float*)(ws + 4800000);         //   400,000
    float* s2d   = (float*)(ws + 5200000);         //   400,000
    int*   deg   = (int*)  (ws + 5600000);         //   400,000
    int*   nptr  = (int*)  (ws + 6000000);         //   400,016
    int*   ccnt  = (int*)  (ws + 6400016);         //     1,564 -> pad
    int*   cbase = (int*)  (ws + 6401600);         //     1,568 -> pad
    int*   cursC = (int*)  (ws + 6403200);         //    25,024 (391 x 16 ints, 64B stride)
    unsigned int* bdata = (unsigned int*)(ws + 6428224);  // 25,600,000

    float* out = (float*)d_out;

    hipMemsetAsync(deg, 0, N_NODES * sizeof(int), stream);

    k0_node<<<(N_NODES + 255) / 256, 256, 0, stream>>>(x, W1, a1s, a1d, h1, s1s, s1d);
    k_hist<<<N_EDGES / 4 / 256, 256, 0, stream>>>(dst, deg);
    k2a_csum<<<NBC, 256, 0, stream>>>(deg, ccnt);
    k2b_cscan<<<1, 512, 0, stream>>>(ccnt, cbase, cursC);
    k2c_nptr<<<NBC, 256, 0, stream>>>(deg, cbase, nptr);
    kA_scatter<<<NA_BLOCKS, 256, 0, stream>>>(src, dst, cursC, bdata);
    kB_sort<<<NBC, 256, 0, stream>>>(cbase, bdata);
    kAgg1<<<(N_NODES * 4 + 255) / 256, 256, 0, stream>>>(nptr, bdata, h1, s1s, s1d,
                                                         b1, W2, a2s, a2d, h2, s2s, s2d);
    kAgg2<<<(N_NODES * 4 + 255) / 256, 256, 0, stream>>>(nptr, bdata, h2, s2s, s2d, b2, out);
}

// Round 6
// 285.342 us; speedup vs baseline: 5.6768x; 1.8523x over previous
//
#include <hip/hip_runtime.h>
#include <math.h>

#define N_NODES 100000
#define N_EDGES 6400000
#define F_IN 36
#define HID 8
#define NCLS 2
#define NEG_SLOPE 0.2f

#define COARSE 256                        // nodes per coarse bucket (dst >> 8)
#define NBC 391                           // ceil(N_NODES/256)
#define CAPC 18432                        // max edges per coarse bucket (mean ~16368, +16 sigma)
#define NA_BLOCKS 256                     // pass-A blocks
#define EPB (N_EDGES / NA_BLOCKS)         // 25000 edges per pass-A block
#define SHIFT1 8.0f                       // softmax shift (softmax is shift-invariant)
#define SHIFT2 16.0f

// ---------------- K0: per-node h1 = x@W1, s1s = h1.a_src, s1d = h1.a_dst ----
__global__ __launch_bounds__(256) void k0_node(
    const float* __restrict__ x, const float* __restrict__ W1,
    const float* __restrict__ a1s_g, const float* __restrict__ a1d_g,
    float* __restrict__ h1, float* __restrict__ s1s, float* __restrict__ s1d)
{
    __shared__ float sW[F_IN * HID];
    __shared__ float sas[HID], sad[HID];
    int tid = threadIdx.x;
    for (int i = tid; i < F_IN * HID; i += 256) sW[i] = W1[i];
    if (tid < HID) { sas[tid] = a1s_g[tid]; sad[tid] = a1d_g[tid]; }
    __syncthreads();

    int n = blockIdx.x * 256 + tid;
    if (n >= N_NODES) return;

    const float4* xp = (const float4*)(x + (size_t)n * F_IN);
    float h[HID];
#pragma unroll
    for (int f = 0; f < HID; ++f) h[f] = 0.f;
#pragma unroll
    for (int q = 0; q < F_IN / 4; ++q) {
        float4 v = xp[q];
        float vs[4] = {v.x, v.y, v.z, v.w};
#pragma unroll
        for (int j = 0; j < 4; ++j) {
            int k = q * 4 + j;
#pragma unroll
            for (int f = 0; f < HID; ++f) h[f] = fmaf(vs[j], sW[k * HID + f], h[f]);
        }
    }
    float ss = 0.f, sd = 0.f;
#pragma unroll
    for (int f = 0; f < HID; ++f) { ss = fmaf(h[f], sas[f], ss); sd = fmaf(h[f], sad[f], sd); }

    float4* hp = (float4*)(h1 + (size_t)n * HID);
    hp[0] = make_float4(h[0], h[1], h[2], h[3]);
    hp[1] = make_float4(h[4], h[5], h[6], h[7]);
    s1s[n] = ss;
    s1d[n] = sd;
}

// ---------------- KC: coarse-bucket histogram (LDS-privatized, 391 bins) ---
__global__ __launch_bounds__(256) void kc_hist(const int* __restrict__ dst, int* __restrict__ ccnt)
{
    __shared__ int lh[NBC];
    int tid = threadIdx.x;
    for (int i = tid; i < NBC; i += 256) lh[i] = 0;
    __syncthreads();
    const int4* dv = (const int4*)dst;
    int total4 = N_EDGES / 4;
    for (int i = blockIdx.x * 256 + tid; i < total4; i += gridDim.x * 256) {
        int4 d = dv[i];
        atomicAdd(&lh[d.x >> 8], 1);
        atomicAdd(&lh[d.y >> 8], 1);
        atomicAdd(&lh[d.z >> 8], 1);
        atomicAdd(&lh[d.w >> 8], 1);
    }
    __syncthreads();
    for (int i = tid; i < NBC; i += 256) if (lh[i]) atomicAdd(&ccnt[i], lh[i]);
}

// ---------------- K2b: scan coarse counts; init padded cursors -------------
__global__ __launch_bounds__(512) void k2b_cscan(const int* __restrict__ ccnt,
                                                 int* __restrict__ cbase, int* __restrict__ cursC)
{
    __shared__ int s[512];
    int tid = threadIdx.x;
    int v = (tid < NBC) ? ccnt[tid] : 0;
    s[tid] = v;
    __syncthreads();
    for (int off = 1; off < 512; off <<= 1) {
        int t = (tid >= off) ? s[tid - off] : 0;
        __syncthreads();
        s[tid] += t;
        __syncthreads();
    }
    int ex = s[tid] - v;
    if (tid < NBC) { cbase[tid] = ex; cursC[tid * 16] = ex; }
    if (tid == NBC) cbase[NBC] = ex;   // == N_EDGES
}

// ---------------- KA: coarse scatter (391 buckets, padded global cursors) --
__global__ __launch_bounds__(256) void kA_scatter(
    const int* __restrict__ src, const int* __restrict__ dst,
    int* __restrict__ cursC, unsigned int* __restrict__ bdata)
{
    __shared__ int lh[NBC];
    __shared__ int lc[NBC];
    int tid = threadIdx.x;
    for (int i = tid; i < NBC; i += 256) lh[i] = 0;
    __syncthreads();

    int e0 = blockIdx.x * EPB;
    const int4* sv = (const int4*)(src + e0);
    const int4* dv = (const int4*)(dst + e0);
    const int n4 = EPB / 4;                       // 6250

    for (int i = tid; i < n4; i += 256) {
        int4 d = dv[i];
        atomicAdd(&lh[d.x >> 8], 1);
        atomicAdd(&lh[d.y >> 8], 1);
        atomicAdd(&lh[d.z >> 8], 1);
        atomicAdd(&lh[d.w >> 8], 1);
    }
    __syncthreads();
    for (int b = tid; b < NBC; b += 256) {
        int c = lh[b];
        lc[b] = c ? atomicAdd(&cursC[b * 16], c) : 0;   // one 64B line per cursor
    }
    __syncthreads();
    for (int i = tid; i < n4; i += 256) {
        int4 d = dv[i];
        int4 s = sv[i];
        int b, p;
        b = d.x >> 8; p = atomicAdd(&lc[b], 1); bdata[p] = (unsigned)s.x | ((unsigned)(d.x & 255) << 17);
        b = d.y >> 8; p = atomicAdd(&lc[b], 1); bdata[p] = (unsigned)s.y | ((unsigned)(d.y & 255) << 17);
        b = d.z >> 8; p = atomicAdd(&lc[b], 1); bdata[p] = (unsigned)s.z | ((unsigned)(d.z & 255) << 17);
        b = d.w >> 8; p = atomicAdd(&lc[b], 1); bdata[p] = (unsigned)s.w | ((unsigned)(d.w & 255) << 17);
    }
}

// ---------------- KB: in-LDS node-granularity sort; emits nptr CSR ---------
__global__ __launch_bounds__(256) void kB_sort(
    const int* __restrict__ cbase, unsigned int* __restrict__ bdata,
    int* __restrict__ nptr)
{
    __shared__ unsigned int raw[CAPC];    // 72 KB
    __shared__ int cnt[COARSE];
    __shared__ int cur[COARSE];
    int tid = threadIdx.x;
    int c = blockIdx.x;
    int cb0 = cbase[c], cb1 = cbase[c + 1];
    int ne = cb1 - cb0;

    cnt[tid] = 0;
    __syncthreads();

    for (int i = tid; i < ne; i += 256) {
        unsigned pk = bdata[cb0 + i];
        raw[i] = pk;
        atomicAdd(&cnt[pk >> 17], 1);     // no return needed -> independent
    }
    __syncthreads();

    int v = cnt[tid];
    for (int off = 1; off < 256; off <<= 1) {
        int t = (tid >= off) ? cnt[tid - off] : 0;
        __syncthreads();
        cnt[tid] += t;
        __syncthreads();
    }
    int ex = cnt[tid] - v;                // exclusive within-bucket offset
    cur[tid] = ex;
    int nid = c * COARSE + tid;
    if (nid <= N_NODES) nptr[nid] = cb0 + ex;   // CSR pointer (nid==N_NODES -> N_EDGES)
    __syncthreads();

    for (int i = tid; i < ne; i += 256) {
        unsigned pk = raw[i];
        int loc = pk >> 17;
        int p = atomicAdd(&cur[loc], 1);
        bdata[cb0 + p] = pk & 0x1FFFF;    // node-sorted: store src only
    }
}

// ---------------- KAgg1: layer-1 CSR aggregation (4 threads/node) ----------
__global__ __launch_bounds__(256) void kAgg1(
    const int* __restrict__ nptr, const unsigned int* __restrict__ bdata,
    const float* __restrict__ h1, const float* __restrict__ s1s, const float* __restrict__ s1d,
    const float* __restrict__ b1, const float* __restrict__ W2,
    const float* __restrict__ a2s, const float* __restrict__ a2d,
    float* __restrict__ h2, float* __restrict__ s2s, float* __restrict__ s2d)
{
    int gi = blockIdx.x * 256 + threadIdx.x;
    int n = gi >> 2, q = gi & 3;
    if (n >= N_NODES) return;

    int e0 = nptr[n], e1 = nptr[n + 1];
    float sdvn = s1d[n];
    float z = 0.f;
    float acc[HID];
#pragma unroll
    for (int f = 0; f < HID; ++f) acc[f] = 0.f;

    for (int j = e0 + q; j < e1; j += 4) {
        int s = bdata[j];
        float e = s1s[s] + sdvn;
        e = (e > 0.f) ? e : NEG_SLOPE * e;
        float p = __expf(e - SHIFT1);
        const float4* hp = (const float4*)(h1 + (size_t)s * HID);
        float4 h0 = hp[0], h4 = hp[1];
        z += p;
        acc[0] += p * h0.x; acc[1] += p * h0.y; acc[2] += p * h0.z; acc[3] += p * h0.w;
        acc[4] += p * h4.x; acc[5] += p * h4.y; acc[6] += p * h4.z; acc[7] += p * h4.w;
    }

#pragma unroll
    for (int off = 1; off < 4; off <<= 1) {
        z += __shfl_xor(z, off);
#pragma unroll
        for (int f = 0; f < HID; ++f) acc[f] += __shfl_xor(acc[f], off);
    }

    if (q == 0) {
        float inv = 1.f / (z + 1e-16f);
        float c0 = 0.f, c1 = 0.f;
#pragma unroll
        for (int f = 0; f < HID; ++f) {
            float hr = fmaxf(acc[f] * inv + b1[f], 0.f);
            c0 = fmaf(hr, W2[f * NCLS + 0], c0);
            c1 = fmaf(hr, W2[f * NCLS + 1], c1);
        }
        ((float2*)h2)[n] = make_float2(c0, c1);
        s2s[n] = c0 * a2s[0] + c1 * a2s[1];
        s2d[n] = c0 * a2d[0] + c1 * a2d[1];
    }
}

// ---------------- KAgg2: layer-2 CSR aggregation + log_softmax -------------
__global__ __launch_bounds__(256) void kAgg2(
    const int* __restrict__ nptr, const unsigned int* __restrict__ bdata,
    const float* __restrict__ h2, const float* __restrict__ s2s, const float* __restrict__ s2d,
    const float* __restrict__ b2, float* __restrict__ out)
{
    int gi = blockIdx.x * 256 + threadIdx.x;
    int n = gi >> 2, q = gi & 3;
    if (n >= N_NODES) return;

    int e0 = nptr[n], e1 = nptr[n + 1];
    float sdvn = s2d[n];
    float z = 0.f, a0 = 0.f, a1 = 0.f;

    for (int j = e0 + q; j < e1; j += 4) {
        int s = bdata[j];
        float e = s2s[s] + sdvn;
        e = (e > 0.f) ? e : NEG_SLOPE * e;
        float p = __expf(e - SHIFT2);
        float2 hv = ((const float2*)h2)[s];
        z += p; a0 += p * hv.x; a1 += p * hv.y;
    }

#pragma unroll
    for (int off = 1; off < 4; off <<= 1) {
        z  += __shfl_xor(z, off);
        a0 += __shfl_xor(a0, off);
        a1 += __shfl_xor(a1, off);
    }

    if (q == 0) {
        float inv = 1.f / (z + 1e-16f);
        float o0 = a0 * inv + b2[0];
        float o1 = a1 * inv + b2[1];
        float mx = fmaxf(o0, o1);
        float lse = mx + __logf(__expf(o0 - mx) + __expf(o1 - mx));
        ((float2*)out)[n] = make_float2(o0 - lse, o1 - lse);
    }
}

// ---------------- host launch ----------------------------------------------
extern "C" void kernel_launch(void* const* d_in, const int* in_sizes, int n_in,
                              void* d_out, int out_size, void* d_ws, size_t ws_size,
                              hipStream_t stream) {
    const float* x   = (const float*)d_in[0];
    const float* W1  = (const float*)d_in[1];
    const float* a1s = (const float*)d_in[2];
    const float* a1d = (const float*)d_in[3];
    const float* b1  = (const float*)d_in[4];
    const float* W2  = (const float*)d_in[5];
    const float* a2s = (const float*)d_in[6];
    const float* a2d = (const float*)d_in[7];
    const float* b2  = (const float*)d_in[8];
    const int*   ei  = (const int*)d_in[9];
    const int* src = ei;
    const int* dst = ei + N_EDGES;

    char* ws = (char*)d_ws;
    float* h1    = (float*)(ws + 0);               // 3,200,000
    float* s1s   = (float*)(ws + 3200000);         //   400,000
    float* s1d   = (float*)(ws + 3600000);         //   400,000
    float* h2    = (float*)(ws + 4000000);         //   800,000
    float* s2s   = (float*)(ws + 4800000);         //   400,000
    float* s2d   = (float*)(ws + 5200000);         //   400,000
    int*   nptr  = (int*)  (ws + 5600000);         //   400,016
    int*   ccnt  = (int*)  (ws + 6000064);         //     1,564 -> pad
    int*   cbase = (int*)  (ws + 6001664);         //     1,568 -> pad
    int*   cursC = (int*)  (ws + 6003264);         //    25,024 (391 x 16 ints, 64B stride)
    unsigned int* bdata = (unsigned int*)(ws + 6028288);  // 25,600,000

    float* out = (float*)d_out;

    hipMemsetAsync(ccnt, 0, NBC * sizeof(int), stream);

    k0_node<<<(N_NODES + 255) / 256, 256, 0, stream>>>(x, W1, a1s, a1d, h1, s1s, s1d);
    kc_hist<<<512, 256, 0, stream>>>(dst, ccnt);
    k2b_cscan<<<1, 512, 0, stream>>>(ccnt, cbase, cursC);
    kA_scatter<<<NA_BLOCKS, 256, 0, stream>>>(src, dst, cursC, bdata);
    kB_sort<<<NBC, 256, 0, stream>>>(cbase, bdata, nptr);
    kAgg1<<<(N_NODES * 4 + 255) / 256, 256, 0, stream>>>(nptr, bdata, h1, s1s, s1d,
                                                         b1, W2, a2s, a2d, h2, s2s, s2d);
    kAgg2<<<(N_NODES * 4 + 255) / 256, 256, 0, stream>>>(nptr, bdata, h2, s2s, s2d, b2, out);
}

// Round 7
// 267.072 us; speedup vs baseline: 6.0651x; 1.0684x over previous
//
#include <hip/hip_runtime.h>
#include <math.h>

#define N_NODES 100000
#define N_EDGES 6400000
#define F_IN 36
#define HID 8
#define NCLS 2
#define NEG_SLOPE 0.2f

#define COARSE 256                        // nodes per coarse bucket (dst >> 8)
#define NBC 391                           // ceil(N_NODES/256)
#define CAPC 18432                        // max edges per coarse bucket (mean ~16368, +16 sigma)
#define NA_BLOCKS 256                     // pass-A blocks
#define EPB (N_EDGES / NA_BLOCKS)         // 25000 edges per pass-A block
#define SHIFT1 8.0f                       // softmax shift (softmax is shift-invariant)
#define SHIFT2 16.0f

// ---------------- K0: per-node h1 = x@W1, s1s = h1.a_src, s1d = h1.a_dst ----
__global__ __launch_bounds__(256) void k0_node(
    const float* __restrict__ x, const float* __restrict__ W1,
    const float* __restrict__ a1s_g, const float* __restrict__ a1d_g,
    float* __restrict__ h1, float* __restrict__ s1s, float* __restrict__ s1d)
{
    __shared__ float sW[F_IN * HID];
    __shared__ float sas[HID], sad[HID];
    int tid = threadIdx.x;
    for (int i = tid; i < F_IN * HID; i += 256) sW[i] = W1[i];
    if (tid < HID) { sas[tid] = a1s_g[tid]; sad[tid] = a1d_g[tid]; }
    __syncthreads();

    int n = blockIdx.x * 256 + tid;
    if (n >= N_NODES) return;

    const float4* xp = (const float4*)(x + (size_t)n * F_IN);
    float h[HID];
#pragma unroll
    for (int f = 0; f < HID; ++f) h[f] = 0.f;
#pragma unroll
    for (int q = 0; q < F_IN / 4; ++q) {
        float4 v = xp[q];
        float vs[4] = {v.x, v.y, v.z, v.w};
#pragma unroll
        for (int j = 0; j < 4; ++j) {
            int k = q * 4 + j;
#pragma unroll
            for (int f = 0; f < HID; ++f) h[f] = fmaf(vs[j], sW[k * HID + f], h[f]);
        }
    }
    float ss = 0.f, sd = 0.f;
#pragma unroll
    for (int f = 0; f < HID; ++f) { ss = fmaf(h[f], sas[f], ss); sd = fmaf(h[f], sad[f], sd); }

    float4* hp = (float4*)(h1 + (size_t)n * HID);
    hp[0] = make_float4(h[0], h[1], h[2], h[3]);
    hp[1] = make_float4(h[4], h[5], h[6], h[7]);
    s1s[n] = ss;
    s1d[n] = sd;
}

// ---------------- KC: coarse-bucket histogram (LDS-privatized, 391 bins) ---
__global__ __launch_bounds__(256) void kc_hist(const int* __restrict__ dst, int* __restrict__ ccnt)
{
    __shared__ int lh[NBC];
    int tid = threadIdx.x;
    for (int i = tid; i < NBC; i += 256) lh[i] = 0;
    __syncthreads();
    const int4* dv = (const int4*)dst;
    int total4 = N_EDGES / 4;
    for (int i = blockIdx.x * 256 + tid; i < total4; i += gridDim.x * 256) {
        int4 d = dv[i];
        atomicAdd(&lh[d.x >> 8], 1);
        atomicAdd(&lh[d.y >> 8], 1);
        atomicAdd(&lh[d.z >> 8], 1);
        atomicAdd(&lh[d.w >> 8], 1);
    }
    __syncthreads();
    for (int i = tid; i < NBC; i += 256) if (lh[i]) atomicAdd(&ccnt[i], lh[i]);
}

// ---------------- K2b: scan coarse counts; init padded cursors -------------
__global__ __launch_bounds__(512) void k2b_cscan(const int* __restrict__ ccnt,
                                                 int* __restrict__ cbase, int* __restrict__ cursC)
{
    __shared__ int s[512];
    int tid = threadIdx.x;
    int v = (tid < NBC) ? ccnt[tid] : 0;
    s[tid] = v;
    __syncthreads();
    for (int off = 1; off < 512; off <<= 1) {
        int t = (tid >= off) ? s[tid - off] : 0;
        __syncthreads();
        s[tid] += t;
        __syncthreads();
    }
    int ex = s[tid] - v;
    if (tid < NBC) { cbase[tid] = ex; cursC[tid * 16] = ex; }
    if (tid == NBC) cbase[NBC] = ex;   // == N_EDGES
}

// ---------------- KA: coarse scatter (391 buckets, padded global cursors) --
__global__ __launch_bounds__(256) void kA_scatter(
    const int* __restrict__ src, const int* __restrict__ dst,
    int* __restrict__ cursC, unsigned int* __restrict__ bdata)
{
    __shared__ int lh[NBC];
    __shared__ int lc[NBC];
    int tid = threadIdx.x;
    for (int i = tid; i < NBC; i += 256) lh[i] = 0;
    __syncthreads();

    int e0 = blockIdx.x * EPB;
    const int4* sv = (const int4*)(src + e0);
    const int4* dv = (const int4*)(dst + e0);
    const int n4 = EPB / 4;                       // 6250

    for (int i = tid; i < n4; i += 256) {
        int4 d = dv[i];
        atomicAdd(&lh[d.x >> 8], 1);
        atomicAdd(&lh[d.y >> 8], 1);
        atomicAdd(&lh[d.z >> 8], 1);
        atomicAdd(&lh[d.w >> 8], 1);
    }
    __syncthreads();
    for (int b = tid; b < NBC; b += 256) {
        int c = lh[b];
        lc[b] = c ? atomicAdd(&cursC[b * 16], c) : 0;   // one 64B line per cursor
    }
    __syncthreads();
    for (int i = tid; i < n4; i += 256) {
        int4 d = dv[i];
        int4 s = sv[i];
        int b, p;
        b = d.x >> 8; p = atomicAdd(&lc[b], 1); bdata[p] = (unsigned)s.x | ((unsigned)(d.x & 255) << 17);
        b = d.y >> 8; p = atomicAdd(&lc[b], 1); bdata[p] = (unsigned)s.y | ((unsigned)(d.y & 255) << 17);
        b = d.z >> 8; p = atomicAdd(&lc[b], 1); bdata[p] = (unsigned)s.z | ((unsigned)(d.z & 255) << 17);
        b = d.w >> 8; p = atomicAdd(&lc[b], 1); bdata[p] = (unsigned)s.w | ((unsigned)(d.w & 255) << 17);
    }
}

// ---------------- KB: in-LDS node-granularity sort; emits nptr CSR ---------
__global__ __launch_bounds__(256) void kB_sort(
    const int* __restrict__ cbase, unsigned int* __restrict__ bdata,
    int* __restrict__ nptr)
{
    __shared__ unsigned int raw[CAPC];    // 72 KB
    __shared__ int cnt[COARSE];
    __shared__ int cur[COARSE];
    int tid = threadIdx.x;
    int c = blockIdx.x;
    int cb0 = cbase[c], cb1 = cbase[c + 1];
    int ne = cb1 - cb0;

    cnt[tid] = 0;
    __syncthreads();

    for (int i = tid; i < ne; i += 256) {
        unsigned pk = bdata[cb0 + i];
        raw[i] = pk;
        atomicAdd(&cnt[pk >> 17], 1);     // no return needed -> independent
    }
    __syncthreads();

    int v = cnt[tid];
    for (int off = 1; off < 256; off <<= 1) {
        int t = (tid >= off) ? cnt[tid - off] : 0;
        __syncthreads();
        cnt[tid] += t;
        __syncthreads();
    }
    int ex = cnt[tid] - v;                // exclusive within-bucket offset
    cur[tid] = ex;
    int nid = c * COARSE + tid;
    if (nid <= N_NODES) nptr[nid] = cb0 + ex;   // CSR pointer (nid==N_NODES -> N_EDGES)
    __syncthreads();

    for (int i = tid; i < ne; i += 256) {
        unsigned pk = raw[i];
        int loc = pk >> 17;
        int p = atomicAdd(&cur[loc], 1);
        bdata[cb0 + p] = pk & 0x1FFFF;    // node-sorted: store src only
    }
}

// ---------------- KAgg1: layer-1 CSR aggregation (8 threads/node, x2 MLP) --
__global__ __launch_bounds__(256) void kAgg1(
    const int* __restrict__ nptr, const unsigned int* __restrict__ bdata,
    const float* __restrict__ h1, const float* __restrict__ s1s, const float* __restrict__ s1d,
    const float* __restrict__ b1, const float* __restrict__ W2,
    const float* __restrict__ a2s, const float* __restrict__ a2d,
    float* __restrict__ h2, float* __restrict__ s2s, float* __restrict__ s2d)
{
    int gi = blockIdx.x * 256 + threadIdx.x;
    int n = gi >> 3, q = gi & 7;
    if (n >= N_NODES) return;

    int e0 = nptr[n], e1 = nptr[n + 1];
    float sdvn = s1d[n];
    float z = 0.f;
    float acc[HID];
#pragma unroll
    for (int f = 0; f < HID; ++f) acc[f] = 0.f;

    int j = e0 + q;
    for (; j + 8 < e1; j += 16) {
        int sA = bdata[j];
        int sB = bdata[j + 8];
        float rA = s1s[sA];
        float rB = s1s[sB];
        const float4* hpA = (const float4*)(h1 + (size_t)sA * HID);
        const float4* hpB = (const float4*)(h1 + (size_t)sB * HID);
        float4 a0 = hpA[0], a4 = hpA[1];
        float4 b0 = hpB[0], b4 = hpB[1];
        float eA = rA + sdvn; eA = (eA > 0.f) ? eA : NEG_SLOPE * eA;
        float eB = rB + sdvn; eB = (eB > 0.f) ? eB : NEG_SLOPE * eB;
        float pA = __expf(eA - SHIFT1);
        float pB = __expf(eB - SHIFT1);
        z += pA + pB;
        acc[0] += pA * a0.x + pB * b0.x;
        acc[1] += pA * a0.y + pB * b0.y;
        acc[2] += pA * a0.z + pB * b0.z;
        acc[3] += pA * a0.w + pB * b0.w;
        acc[4] += pA * a4.x + pB * b4.x;
        acc[5] += pA * a4.y + pB * b4.y;
        acc[6] += pA * a4.z + pB * b4.z;
        acc[7] += pA * a4.w + pB * b4.w;
    }
    if (j < e1) {
        int s = bdata[j];
        float e = s1s[s] + sdvn;
        e = (e > 0.f) ? e : NEG_SLOPE * e;
        float p = __expf(e - SHIFT1);
        const float4* hp = (const float4*)(h1 + (size_t)s * HID);
        float4 h0 = hp[0], h4 = hp[1];
        z += p;
        acc[0] += p * h0.x; acc[1] += p * h0.y; acc[2] += p * h0.z; acc[3] += p * h0.w;
        acc[4] += p * h4.x; acc[5] += p * h4.y; acc[6] += p * h4.z; acc[7] += p * h4.w;
    }

#pragma unroll
    for (int off = 1; off < 8; off <<= 1) {
        z += __shfl_xor(z, off);
#pragma unroll
        for (int f = 0; f < HID; ++f) acc[f] += __shfl_xor(acc[f], off);
    }

    if (q == 0) {
        float inv = 1.f / (z + 1e-16f);
        float c0 = 0.f, c1 = 0.f;
#pragma unroll
        for (int f = 0; f < HID; ++f) {
            float hr = fmaxf(acc[f] * inv + b1[f], 0.f);
            c0 = fmaf(hr, W2[f * NCLS + 0], c0);
            c1 = fmaf(hr, W2[f * NCLS + 1], c1);
        }
        ((float2*)h2)[n] = make_float2(c0, c1);
        s2s[n] = c0 * a2s[0] + c1 * a2s[1];
        s2d[n] = c0 * a2d[0] + c1 * a2d[1];
    }
}

// ---------------- KAgg2: layer-2 CSR aggregation (8 threads/node, x2 MLP) --
__global__ __launch_bounds__(256) void kAgg2(
    const int* __restrict__ nptr, const unsigned int* __restrict__ bdata,
    const float* __restrict__ h2, const float* __restrict__ s2s, const float* __restrict__ s2d,
    const float* __restrict__ b2, float* __restrict__ out)
{
    int gi = blockIdx.x * 256 + threadIdx.x;
    int n = gi >> 3, q = gi & 7;
    if (n >= N_NODES) return;

    int e0 = nptr[n], e1 = nptr[n + 1];
    float sdvn = s2d[n];
    float z = 0.f, a0 = 0.f, a1 = 0.f;

    int j = e0 + q;
    for (; j + 8 < e1; j += 16) {
        int sA = bdata[j];
        int sB = bdata[j + 8];
        float rA = s2s[sA];
        float rB = s2s[sB];
        float2 hA = ((const float2*)h2)[sA];
        float2 hB = ((const float2*)h2)[sB];
        float eA = rA + sdvn; eA = (eA > 0.f) ? eA : NEG_SLOPE * eA;
        float eB = rB + sdvn; eB = (eB > 0.f) ? eB : NEG_SLOPE * eB;
        float pA = __expf(eA - SHIFT2);
        float pB = __expf(eB - SHIFT2);
        z += pA + pB;
        a0 += pA * hA.x + pB * hB.x;
        a1 += pA * hA.y + pB * hB.y;
    }
    if (j < e1) {
        int s = bdata[j];
        float e = s2s[s] + sdvn;
        e = (e > 0.f) ? e : NEG_SLOPE * e;
        float p = __expf(e - SHIFT2);
        float2 hv = ((const float2*)h2)[s];
        z += p; a0 += p * hv.x; a1 += p * hv.y;
    }

#pragma unroll
    for (int off = 1; off < 8; off <<= 1) {
        z  += __shfl_xor(z, off);
        a0 += __shfl_xor(a0, off);
        a1 += __shfl_xor(a1, off);
    }

    if (q == 0) {
        float inv = 1.f / (z + 1e-16f);
        float o0 = a0 * inv + b2[0];
        float o1 = a1 * inv + b2[1];
        float mx = fmaxf(o0, o1);
        float lse = mx + __logf(__expf(o0 - mx) + __expf(o1 - mx));
        ((float2*)out)[n] = make_float2(o0 - lse, o1 - lse);
    }
}

// ---------------- host launch ----------------------------------------------
extern "C" void kernel_launch(void* const* d_in, const int* in_sizes, int n_in,
                              void* d_out, int out_size, void* d_ws, size_t ws_size,
                              hipStream_t stream) {
    const float* x   = (const float*)d_in[0];
    const float* W1  = (const float*)d_in[1];
    const float* a1s = (const float*)d_in[2];
    const float* a1d = (const float*)d_in[3];
    const float* b1  = (const float*)d_in[4];
    const float* W2  = (const float*)d_in[5];
    const float* a2s = (const float*)d_in[6];
    const float* a2d = (const float*)d_in[7];
    const float* b2  = (const float*)d_in[8];
    const int*   ei  = (const int*)d_in[9];
    const int* src = ei;
    const int* dst = ei + N_EDGES;

    char* ws = (char*)d_ws;
    float* h1    = (float*)(ws + 0);               // 3,200,000
    float* s1s   = (float*)(ws + 3200000);         //   400,000
    float* s1d   = (float*)(ws + 3600000);         //   400,000
    float* h2    = (float*)(ws + 4000000);         //   800,000
    float* s2s   = (float*)(ws + 4800000);         //   400,000
    float* s2d   = (float*)(ws + 5200000);         //   400,000
    int*   nptr  = (int*)  (ws + 5600000);         //   400,016
    int*   ccnt  = (int*)  (ws + 6000064);         //     1,564 -> pad
    int*   cbase = (int*)  (ws + 6001664);         //     1,568 -> pad
    int*   cursC = (int*)  (ws + 6003264);         //    25,024 (391 x 16 ints, 64B stride)
    unsigned int* bdata = (unsigned int*)(ws + 6028288);  // 25,600,000

    float* out = (float*)d_out;

    hipMemsetAsync(ccnt, 0, NBC * sizeof(int), stream);

    k0_node<<<(N_NODES + 255) / 256, 256, 0, stream>>>(x, W1, a1s, a1d, h1, s1s, s1d);
    kc_hist<<<512, 256, 0, stream>>>(dst, ccnt);
    k2b_cscan<<<1, 512, 0, stream>>>(ccnt, cbase, cursC);
    kA_scatter<<<NA_BLOCKS, 256, 0, stream>>>(src, dst, cursC, bdata);
    kB_sort<<<NBC, 256, 0, stream>>>(cbase, bdata, nptr);
    kAgg1<<<(N_NODES * 8 + 255) / 256, 256, 0, stream>>>(nptr, bdata, h1, s1s, s1d,
                                                         b1, W2, a2s, a2d, h2, s2s, s2d);
    kAgg2<<<(N_NODES * 8 + 255) / 256, 256, 0, stream>>>(nptr, bdata, h2, s2s, s2d, b2, out);
}